// Round 8
// baseline (659.246 us; speedup 1.0000x reference)
//
#include <hip/hip_runtime.h>
#include <hip/hip_bf16.h>

#define N_NODES 8192
#define IN_FEAT 256
#define OUT_F   64
#define NHEAD   4
#define HF      256     // NHEAD*OUT_F
#define NEG     0.2f
#define SUPPT_LD 8224   // 8192 + 32: breaks 16KB power-of-2 stride camping
#define LOG2E   1.442695041f

typedef unsigned short u16;
typedef unsigned int   u32;
typedef __attribute__((ext_vector_type(8))) short short8;   // 8 bf16 (4 VGPRs)
typedef __attribute__((ext_vector_type(4))) float f32x4;    // MFMA C/D

__device__ __forceinline__ u16 f2bf(float f) {
    union { unsigned int u; float f; } v; v.f = f;
    unsigned int r = v.u + 0x7FFFu + ((v.u >> 16) & 1u);  // RNE
    return (u16)(r >> 16);
}
__device__ __forceinline__ float leaky(float x) {
    return fmaxf(x, NEG * x);   // valid for 0 < NEG < 1
}

// ---------------------------------------------------------------------------
// K1: per 8 rows: suppT = (X@W)^T (bf16, o-major, padded LD), f1/f2 dots,
//     proj = X@Pw^T + proj_b + bias -> straight into d_out.
// ---------------------------------------------------------------------------
#define RPB 8
__global__ __launch_bounds__(256) void k_gemm(
    const float* __restrict__ inp,   // [N, 256]
    const float* __restrict__ W,     // [256, 256] (k-major rows)
    const float* __restrict__ U,     // [H*64] flat
    const float* __restrict__ V,     // [H*64] flat
    const float* __restrict__ Bias,  // [256]
    const float* __restrict__ PW,    // [256 out][256 in]
    const float* __restrict__ PB,    // [256]
    u16*   __restrict__ suppT,       // [256 (h*64+o)][SUPPT_LD] bf16
    float* __restrict__ f1,          // [H][N]
    float* __restrict__ f2,          // [H][N]
    float* __restrict__ outp)        // [N][256]  proj + bias + proj_b
{
    __shared__ __align__(16) float in_lds[RPB][IN_FEAT];
    const int c  = threadIdx.x;            // output column 0..255
    const int n0 = blockIdx.x * RPB;

    #pragma unroll
    for (int r = 0; r < RPB; ++r)
        in_lds[r][c] = inp[(size_t)(n0 + r) * IN_FEAT + c];
    __syncthreads();

    float accs[RPB], accp[RPB];
    #pragma unroll
    for (int r = 0; r < RPB; ++r) { accs[r] = 0.f; accp[r] = 0.f; }
    const float* pwrow = PW + (size_t)c * IN_FEAT;
    const float* wp    = W + c;

    // prefetch k=0..3
    float4 pwc = *(const float4*)(pwrow);
    float  w0 = wp[0], w1 = wp[HF], w2 = wp[2 * HF], w3 = wp[3 * HF];

    for (int k = 0; k < IN_FEAT; k += 4) {
        float4 pwn; float wn0, wn1, wn2, wn3;
        const int kn = k + 4;
        if (kn < IN_FEAT) {                       // uniform branch
            pwn = *(const float4*)(pwrow + kn);
            wn0 = wp[(kn + 0) * HF]; wn1 = wp[(kn + 1) * HF];
            wn2 = wp[(kn + 2) * HF]; wn3 = wp[(kn + 3) * HF];
        }
        #pragma unroll
        for (int r = 0; r < RPB; ++r) {
            const float4 xv = *(const float4*)&in_lds[r][k];
            accs[r] = fmaf(xv.x, w0, accs[r]);
            accs[r] = fmaf(xv.y, w1, accs[r]);
            accs[r] = fmaf(xv.z, w2, accs[r]);
            accs[r] = fmaf(xv.w, w3, accs[r]);
            accp[r] = fmaf(xv.x, pwc.x, accp[r]);
            accp[r] = fmaf(xv.y, pwc.y, accp[r]);
            accp[r] = fmaf(xv.z, pwc.z, accp[r]);
            accp[r] = fmaf(xv.w, pwc.w, accp[r]);
        }
        pwc = pwn; w0 = wn0; w1 = wn1; w2 = wn2; w3 = wn3;
    }

    const int lane = c & 63;
    const int h = c >> 6;
    const float uv = U[c], vv = V[c];
    const float bb = Bias[c] + PB[c];

    // suppT row c, cols n0..n0+7: one 16-B store (stride 16448 B, non-pow2)
    union { uint4 v; u16 s[8]; } sp;
    #pragma unroll
    for (int r = 0; r < RPB; ++r) sp.s[r] = f2bf(accs[r]);
    *(uint4*)(suppT + (size_t)c * SUPPT_LD + n0) = sp.v;

    #pragma unroll
    for (int r = 0; r < RPB; ++r) {
        const int n = n0 + r;
        const float sv = accs[r];
        float s1 = sv * uv, s2 = sv * vv;
        #pragma unroll
        for (int mm = 32; mm > 0; mm >>= 1) {
            s1 += __shfl_xor(s1, mm);
            s2 += __shfl_xor(s2, mm);
        }
        if (lane == 0) {
            f1[h * N_NODES + n] = s1;
            f2[h * N_NODES + n] = s2;
        }
        outp[(size_t)n * HF + c] = accp[r] + bb;
    }
}

// ---------------------------------------------------------------------------
// K_pack: adj [N,N] fp32 -> bit matrix [N][256] u32 (bit j%32 of word j/32).
//   One HBM-rate streaming pass; k_attn then never touches the 256 MB again.
// ---------------------------------------------------------------------------
__global__ __launch_bounds__(256) void k_pack(const float* __restrict__ adj,
                                              u32* __restrict__ bits) {
    const size_t gid = (size_t)blockIdx.x * 256 + threadIdx.x;  // word index
    const float* src = adj + gid * 32;
    unsigned m = 0;
    #pragma unroll
    for (int q = 0; q < 8; ++q) {
        const float4 v = *(const float4*)(src + q * 4);
        m |= ((unsigned)(v.x != 0.f) << (q * 4 + 0))
           | ((unsigned)(v.y != 0.f) << (q * 4 + 1))
           | ((unsigned)(v.z != 0.f) << (q * 4 + 2))
           | ((unsigned)(v.w != 0.f) << (q * 4 + 3));
    }
    bits[gid] = m;
}

// ---------------------------------------------------------------------------
// K2: per-head global max of f1 (softmax shift upper bound; leaky monotone).
// ---------------------------------------------------------------------------
__global__ __launch_bounds__(256) void k_f1max(const float* __restrict__ f1,
                                               float* __restrict__ f1max) {
    __shared__ float red[256];
    const int h = blockIdx.x;
    float m = -1e30f;
    for (int j = threadIdx.x; j < N_NODES; j += 256)
        m = fmaxf(m, f1[h * N_NODES + j]);
    red[threadIdx.x] = m;
    __syncthreads();
    for (int s = 128; s > 0; s >>= 1) {
        if (threadIdx.x < s) red[threadIdx.x] = fmaxf(red[threadIdx.x], red[threadIdx.x + s]);
        __syncthreads();
    }
    if (threadIdx.x == 0) f1max[h] = red[0];
}

// ---------------------------------------------------------------------------
// K3: MFMA attention. block = (i-tile 16, head); wave w = j-quarter (2048 j).
//   Adjacency from the packed bit matrix (16 KB LDS per block, L2/L3-hot).
//   Inner loop identical in structure to the round-5/6 verified version:
//   e-tile in A-layout regs, B = 4 x uint4 from suppT (o-major), 4 MFMAs.
//   Cross-wave reduction via LDS atomics; block owns its out slice -> plain
//   RMW store, no global atomics, no extra kernel.
// ---------------------------------------------------------------------------
#define TI 16
#define NTILE (N_NODES / TI)       // 512 i-tiles
#define JQ    (N_NODES / 4)        // 2048 j per wave

__global__ __launch_bounds__(256, 4) void k_attn_mfma(
    const u32* __restrict__ abitg,   // [N][256] packed adjacency bits
    const u16* __restrict__ suppT,   // [256][SUPPT_LD] bf16 (row = h*64+o)
    const float* __restrict__ f1,    // [H][N]
    const float* __restrict__ f2,    // [H][N]
    const float* __restrict__ f1max, // [H]
    float* __restrict__ out)         // [N][256] fp32: proj in, proj+attn out
{
    __shared__ u32   abw[TI][260];   // bit words, pitch 260 (2-way banks max)
    __shared__ float accL[TI][68];   // numerator reduce, pitch 68
    __shared__ float lsumL[TI];

    const int h    = blockIdx.x & 3;
    const int i0   = (blockIdx.x >> 2) * TI;
    const int tid  = threadIdx.x;
    const int wid  = tid >> 6;        // wave = j-quarter
    const int lane = tid & 63;
    const int col  = lane & 15;       // m (A) / n (B) / col (C)
    const int quad = lane >> 4;

    // ---- stage adjacency bit words: thread t -> row t>>4, 16 words ----
    {
        const int r = tid >> 4, c0 = (tid & 15) * 16;
        const u32* src = abitg + (size_t)(i0 + r) * 256 + c0;
        #pragma unroll
        for (int q = 0; q < 4; ++q) {
            const uint4 v = *(const uint4*)(src + q * 4);
            abw[r][c0 + q * 4 + 0] = v.x;
            abw[r][c0 + q * 4 + 1] = v.y;
            abw[r][c0 + q * 4 + 2] = v.z;
            abw[r][c0 + q * 4 + 3] = v.w;
        }
    }
    for (int p = tid; p < TI * 68; p += 256) (&accL[0][0])[p] = 0.f;
    if (tid < TI) lsumL[tid] = 0.f;
    __syncthreads();

    // ---- per-wave j-quarter flash loop ----
    const float f2i = f2[(size_t)h * N_NODES + i0 + col];       // i = col
    const float mi  = leaky(f1max[h] + f2i);                    // >= row max
    const float nmi = -mi * LOG2E;
    const float C1 = LOG2E, C2 = NEG * LOG2E;

    const int jq0 = wid * JQ + (quad << 3);
    const float* f1p = f1 + (size_t)h * N_NODES + jq0;
    const u16*   bp0 = suppT + (size_t)(h * 64 + col) * SUPPT_LD + jq0;
    const int    w0  = wid * (JQ / 32);     // first bit-word of this quarter

    f32x4 acc[4];
    #pragma unroll
    for (int t = 0; t < 4; ++t) acc[t] = (f32x4){0.f, 0.f, 0.f, 0.f};
    float lsum = 0.f;

    for (int jl = 0; jl < JQ; jl += 32) {
        const unsigned word = abw[col][w0 + (jl >> 5)];
        const unsigned bwv  = (word >> (quad << 3)) & 0xffu;
        const float4 fa = *(const float4*)(f1p + jl);
        const float4 fb = *(const float4*)(f1p + jl + 4);

        const float fj[8] = {fa.x, fa.y, fa.z, fa.w, fb.x, fb.y, fb.z, fb.w};
        float e[8];
        #pragma unroll
        for (int jj = 0; jj < 8; ++jj) {
            const float ts = fj[jj] + f2i;
            const float a1 = fmaf(ts, C1, nmi);
            const float a2 = fmaf(ts, C2, nmi);
            const float ex = __builtin_amdgcn_exp2f(fmaxf(a1, a2));
            e[jj] = ((bwv >> jj) & 1) ? ex : 0.f;
            lsum += e[jj];
        }
        union { short8 v; __hip_bfloat162 h2[4]; } af;
        #pragma unroll
        for (int p = 0; p < 4; ++p)
            af.h2[p] = __float22bfloat162_rn(make_float2(e[2 * p], e[2 * p + 1]));

        #pragma unroll
        for (int t = 0; t < 4; ++t) {
            union { uint4 u; short8 s; } bb;
            bb.u = *(const uint4*)(bp0 + (size_t)(t << 4) * SUPPT_LD + jl);
            acc[t] = __builtin_amdgcn_mfma_f32_16x16x32_bf16(af.v, bb.s, acc[t], 0, 0, 0);
        }
    }

    // ---- block-local reduction (LDS atomics; no global atomics) ----
    lsum += __shfl_xor(lsum, 16);
    lsum += __shfl_xor(lsum, 32);   // lane L: quarter-sum for i = L&15
    if (lane < 16) atomicAdd(&lsumL[col], lsum);

    #pragma unroll
    for (int reg = 0; reg < 4; ++reg) {
        const int irow = (quad << 2) + reg;                     // C-layout row
        #pragma unroll
        for (int t = 0; t < 4; ++t)
            atomicAdd(&accL[irow][col + (t << 4)], acc[t][reg]);
    }
    __syncthreads();

    // ---- epilogue: out += accL / lsumL (block owns slice, plain RMW) ----
    #pragma unroll
    for (int p = 0; p < 4; ++p) {
        const int e2 = p * 256 + tid;        // 0..1023
        const int ir = e2 >> 6, o = e2 & 63;
        out[(size_t)(i0 + ir) * HF + (h << 6) + o] += accL[ir][o] / lsumL[ir];
    }
}

// ---------------------------------------------------------------------------
extern "C" void kernel_launch(void* const* d_in, const int* in_sizes, int n_in,
                              void* d_out, int out_size, void* d_ws, size_t ws_size,
                              hipStream_t stream) {
    const float* inp  = (const float*)d_in[0];  // [8192,256]
    const float* adj  = (const float*)d_in[1];  // [8192,8192]
    const float* W    = (const float*)d_in[2];  // [256,256]
    const float* U    = (const float*)d_in[3];  // [4,64,1]
    const float* V    = (const float*)d_in[4];  // [4,64,1]
    const float* Bias = (const float*)d_in[5];  // [1,256]
    const float* PW   = (const float*)d_in[6];  // [256,256]
    const float* PB   = (const float*)d_in[7];  // [256]
    float* out = (float*)d_out;                 // [8192,256] fp32

    char* ws = (char*)d_ws;
    size_t off = 0;
    u16*   suppT = (u16*)(ws + off);   off += (size_t)HF * SUPPT_LD * 2;    // 4.21 MiB
    float* f1    = (float*)(ws + off); off += (size_t)NHEAD * N_NODES * 4;  // 128 KiB
    float* f2    = (float*)(ws + off); off += (size_t)NHEAD * N_NODES * 4;  // 128 KiB
    float* f1mx  = (float*)(ws + off); off += 256;
    u32*   abitg = (u32*)(ws + off);   off += (size_t)N_NODES * 256 * 4;    // 8 MiB
    // total ws use ~12.5 MiB

    k_gemm<<<N_NODES / RPB, 256, 0, stream>>>(inp, W, U, V, Bias, PW, PB,
                                              suppT, f1, f2, out);
    k_pack<<<(N_NODES / 32) * (N_NODES / 256), 256, 0, stream>>>(adj, abitg);
    k_f1max<<<NHEAD, 256, 0, stream>>>(f1, f1mx);
    k_attn_mfma<<<NTILE * NHEAD, 256, 0, stream>>>(abitg, suppT, f1, f2, f1mx, out);
}